// Round 6
// baseline (25998.019 us; speedup 1.0000x reference)
//
#include <hip/hip_runtime.h>
#include <cstdint>
#include <math.h>

#define B_ 512
#define S_ 100
#define E_ 256
#define H_ 256

__device__ __forceinline__ float sigmoidf_(float x){ return 1.0f/(1.0f+expf(-x)); }

// Threefry-2x32, 20 rounds — matches jax/_src/prng.py lowering exactly.
__device__ __forceinline__ void threefry2x32_(uint32_t k0, uint32_t k1,
                                              uint32_t c0, uint32_t c1,
                                              uint32_t& o0, uint32_t& o1){
  uint32_t ks2 = k0 ^ k1 ^ 0x1BD11BDAu;
  uint32_t x0 = c0 + k0, x1 = c1 + k1;
#define ROT_(x,d) (((x)<<(d))|((x)>>(32-(d))))
#define RND_(r) { x0 += x1; x1 = ROT_(x1,(r)); x1 ^= x0; }
  RND_(13) RND_(15) RND_(26) RND_(6)  x0 += k1;  x1 += ks2 + 1u;
  RND_(17) RND_(29) RND_(16) RND_(24) x0 += ks2; x1 += k0  + 2u;
  RND_(13) RND_(15) RND_(26) RND_(6)  x0 += k0;  x1 += k1  + 3u;
  RND_(17) RND_(29) RND_(16) RND_(24) x0 += k1;  x1 += ks2 + 4u;
  RND_(13) RND_(15) RND_(26) RND_(6)  x0 += ks2; x1 += k0  + 5u;
#undef RND_
#undef ROT_
  o0 = x0; o1 = x1;
}

__device__ __forceinline__ float gumbel_bits_(uint32_t bits){
  const float tiny = 1.175494350822287508e-38f;
  float u = __uint_as_float((bits >> 9) | 0x3f800000u) - 1.0f; // [0,1)
  u = fmaxf(tiny, u + tiny);
  return -logf(-logf(u));
}

__device__ __forceinline__ float wsum_(float v){
  #pragma unroll
  for (int d = 32; d > 0; d >>= 1) v += __shfl_xor(v, d, 64);
  return v;
}
__device__ __forceinline__ float wmax_(float v){
  #pragma unroll
  for (int d = 32; d > 0; d >>= 1) v = fmaxf(v, __shfl_xor(v, d, 64));
  return v;
}

struct KParams {
  const float *inputs, *emb;
  const float *gbq, *gV, *pbq, *pV;
  const float *gbr, *pbr;
  const float *start;
  const float *W4E, *W4D, *b4E, *b4D, *gWqS, *pWqS, *gWrT, *pWrT;
  float *enc, *rgS, *rpS;
  float *probs, *idxo;
};

struct PrepParams {
  const float *eWih, *eWhh, *ebih, *ebhh;
  const float *dWih, *dWhh, *dbih, *dbhh;
  const float *gWq, *pWq, *gWr, *pWr;
  float *W4E, *W4D, *b4E, *b4D, *gWqS, *pWqS, *gWrT, *pWrT;
};

// ---------- single fused prep kernel ----------
__global__ __launch_bounds__(256) void prep_all(PrepParams P){
  const int i = blockIdx.x*256 + threadIdx.x;        // 0 .. 524287
  {
    const int g = i & 3, u2 = (i >> 2) & 255, k = i >> 10;
    const int row = g*256 + u2;
    P.W4E[i] = (k < 256) ? P.eWih[row*256 + k] : P.eWhh[row*256 + (k-256)];
    P.W4D[i] = (k < 256) ? P.dWih[row*256 + k] : P.dWhh[row*256 + (k-256)];
  }
  if (i < 65536) {
    // plain transposes for the ref-projection GEMMs
    const int r = i >> 8, cc = i & 255;
    P.gWrT[i] = P.gWr[cc*256 + r];
    P.pWrT[i] = P.pWr[cc*256 + r];
    // k-quad swizzle for the attention matvecs: gWqS[kq][u][j] = gWq[u][4kq+j]
    const int j = i & 3, uq = (i >> 2) & 255, kq = i >> 10;
    P.gWqS[i] = P.gWq[uq*256 + kq*4 + j];
    P.pWqS[i] = P.pWq[uq*256 + kq*4 + j];
  }
  if (i < 1024) {
    const int g = i & 3, u2 = i >> 2;
    P.b4E[i] = P.ebih[g*256 + u2] + P.ebhh[g*256 + u2];
    P.b4D[i] = P.dbih[g*256 + u2] + P.dbhh[g*256 + u2];
  }
}

// ---------- THE kernel: 512 threads, block owns batch rows 2*bid, 2*bid+1 ----------
__global__ __launch_bounds__(512, 2) void pointer_net_perb(KParams P)
{
  const int tid  = threadIdx.x;       // 0..511
  const int u    = tid & 255;         // unit
  const int half = tid >> 8;          // 0/1: LSTM gate-half / cell row / attention row
  const int lane = tid & 63;
  const int wv   = tid >> 6;          // 0..7
  const int wvL  = wv & 3;            // wave within bb-group
  const int wbb  = wv >> 2;           // bb handled by this wave in glimpse/pointer
  const int b0   = blockIdx.x * 2;

  __shared__ float embL[512];
  __shared__ float xs[512];           // [k(256)][r(2)]
  __shared__ float hs[512];           // [u(256)][r(2)]
  __shared__ int   maskL[256];        // [bb][s(128)]
  __shared__ int   selL[2];
  __shared__ union UU {
    float es[2][5120];                // phase-2 staging [bb][s(20)][k(256)]
    struct {
      float gbuf[2048];               // [u][r][g]
      float qqL[512], qL[512], pqL[512];   // [bb][u]
      float lg[256], alpha[256], lp[256];  // [bb][s(128)]
    } s;
  } uu;

  // ---- init ----
  embL[tid] = P.emb[tid];
  if (tid < 256) maskL[tid] = 0;
  if (tid < 2) selL[tid] = -1;
  hs[tid] = 0.f;
  float cc = 0.f;
  const float gvx = P.gV[lane], gvy = P.gV[lane+64], gvz = P.gV[lane+128], gvw = P.gV[lane+192];
  const float pvx = P.pV[lane], pvy = P.pV[lane+64], pvz = P.pV[lane+128], pvw = P.pV[lane+192];
  __syncthreads();

  // =============== Phase 1: encoder, 100 steps ===============
  for (int t = 0; t < S_; ++t) {
    { const int k = tid >> 1, r = tid & 1, b = b0 + r;
      xs[tid] = P.inputs[b*200 + t]*embL[k] + P.inputs[b*200 + 100 + t]*embL[256 + k]; }
    __syncthreads();

    float a0x=0.f,a0y=0.f,a1x=0.f,a1y=0.f;     // rows 0/1, gates (2*half, 2*half+1)
    const float* wp = P.W4E + (size_t)u*4 + half*2;
    #pragma unroll 8
    for (int k = 0; k < 256; ++k) {
      const float2 w = *(const float2*)(wp + (size_t)k*1024);
      const float2 x = *(const float2*)(xs + k*2);
      a0x += x.x*w.x; a0y += x.x*w.y; a1x += x.y*w.x; a1y += x.y*w.y;
    }
    #pragma unroll 8
    for (int k = 256; k < 512; ++k) {
      const float2 w = *(const float2*)(wp + (size_t)k*1024);
      const float2 x = *(const float2*)(hs + (k-256)*2);
      a0x += x.x*w.x; a0y += x.x*w.y; a1x += x.y*w.x; a1y += x.y*w.y;
    }
    uu.s.gbuf[u*8 + 0 + half*2]     = a0x;
    uu.s.gbuf[u*8 + 0 + half*2 + 1] = a0y;
    uu.s.gbuf[u*8 + 4 + half*2]     = a1x;
    uu.s.gbuf[u*8 + 4 + half*2 + 1] = a1y;
    __syncthreads();
    {
      const float4 g4  = *(const float4*)(uu.s.gbuf + u*8 + half*4);
      const float4 bb4 = *(const float4*)(P.b4E + u*4);
      const float gi = g4.x + bb4.x, gf = g4.y + bb4.y, gg = g4.z + bb4.z, go = g4.w + bb4.w;
      const float cN = sigmoidf_(gf)*cc + sigmoidf_(gi)*tanhf(gg);
      const float hN = sigmoidf_(go)*tanhf(cN);
      cc = cN; hs[u*2 + half] = hN;
      P.enc[((size_t)(b0+half)*S_ + t)*H_ + u] = hN;
    }
    __syncthreads();
  }

  // =============== Phase 2: ref projections, both rows in parallel halves ===============
  for (int s0 = 0; s0 < S_; s0 += 20) {
    for (int i = u; i < 5120; i += 256)
      uu.es[half][i] = P.enc[((size_t)(b0+half)*S_ + s0 + (i >> 8))*H_ + (i & 255)];
    __syncthreads();
    float accg[20], accp[20];
    #pragma unroll
    for (int s = 0; s < 20; ++s) { accg[s] = 0.f; accp[s] = 0.f; }
    #pragma unroll 4
    for (int k = 0; k < 256; ++k) {
      const float wg  = P.gWrT[k*256 + u];
      const float wpv = P.pWrT[k*256 + u];
      #pragma unroll
      for (int s = 0; s < 20; ++s) {
        const float xk = uu.es[half][s*256 + k];
        accg[s] += xk*wg; accp[s] += xk*wpv;
      }
    }
    const float bg = P.gbr[u], bp = P.pbr[u];
    const int usw = (u & 63)*4 + (u >> 6);     // swizzled store: [s][lane][j]
    #pragma unroll
    for (int s = 0; s < 20; ++s) {
      P.rgS[((size_t)(b0+half)*S_ + s0 + s)*256 + usw] = accg[s] + bg;
      P.rpS[((size_t)(b0+half)*S_ + s0 + s)*256 + usw] = accp[s] + bp;
    }
    __syncthreads();
  }

  // =============== Phase 3: decoder, 100 steps ===============
  for (int t = 0; t < S_; ++t) {
    { const int k = tid >> 1, r = tid & 1, b = b0 + r;
      const int s = selL[r];
      xs[tid] = (s < 0) ? P.start[k]
              : P.inputs[b*200 + s]*embL[k] + P.inputs[b*200 + 100 + s]*embL[256 + k]; }
    __syncthreads();

    float a0x=0.f,a0y=0.f,a1x=0.f,a1y=0.f;
    const float* wp = P.W4D + (size_t)u*4 + half*2;
    #pragma unroll 8
    for (int k = 0; k < 256; ++k) {
      const float2 w = *(const float2*)(wp + (size_t)k*1024);
      const float2 x = *(const float2*)(xs + k*2);
      a0x += x.x*w.x; a0y += x.x*w.y; a1x += x.y*w.x; a1y += x.y*w.y;
    }
    #pragma unroll 8
    for (int k = 256; k < 512; ++k) {
      const float2 w = *(const float2*)(wp + (size_t)k*1024);
      const float2 x = *(const float2*)(hs + (k-256)*2);
      a0x += x.x*w.x; a0y += x.x*w.y; a1x += x.y*w.x; a1y += x.y*w.y;
    }
    uu.s.gbuf[u*8 + 0 + half*2]     = a0x;
    uu.s.gbuf[u*8 + 0 + half*2 + 1] = a0y;
    uu.s.gbuf[u*8 + 4 + half*2]     = a1x;
    uu.s.gbuf[u*8 + 4 + half*2 + 1] = a1y;
    __syncthreads();
    {
      const float4 g4  = *(const float4*)(uu.s.gbuf + u*8 + half*4);
      const float4 bb4 = *(const float4*)(P.b4D + u*4);
      const float gi = g4.x + bb4.x, gf = g4.y + bb4.y, gg = g4.z + bb4.z, go = g4.w + bb4.w;
      const float cN = sigmoidf_(gf)*cc + sigmoidf_(gi)*tanhf(gg);
      const float hN = sigmoidf_(go)*tanhf(cN);
      cc = cN; hs[u*2 + half] = hN;
    }
    __syncthreads();

    // ---- qq = g_bq + h @ g_Wq^T ----
    { float a = P.gbq[u];
      const float4* wq = (const float4*)P.gWqS + u;
      #pragma unroll 4
      for (int kq = 0; kq < 64; ++kq) {
        const float4 w = wq[(size_t)kq*256];
        a += hs[(4*kq+0)*2 + half]*w.x;
        a += hs[(4*kq+1)*2 + half]*w.y;
        a += hs[(4*kq+2)*2 + half]*w.z;
        a += hs[(4*kq+3)*2 + half]*w.w;
      }
      uu.s.qqL[half*256 + u] = a; }
    __syncthreads();

    // ---- glimpse logits (waves 0-3: bb=0, waves 4-7: bb=1) ----
    {
      const float q0 = uu.s.qqL[wbb*256 + lane];
      const float q1 = uu.s.qqL[wbb*256 + lane + 64];
      const float q2 = uu.s.qqL[wbb*256 + lane + 128];
      const float q3 = uu.s.qqL[wbb*256 + lane + 192];
      const float* rgb = P.rgS + (size_t)(b0+wbb)*S_*H_;
      const int* mk = maskL + wbb*128;
      for (int is = 0; is < 25; ++is) {
        const int s = is*4 + wvL;
        const float4 r4 = *(const float4*)(rgb + s*256 + lane*4);
        float pp = gvx*tanhf(q0 + r4.x);
        pp += gvy*tanhf(q1 + r4.y);
        pp += gvz*tanhf(q2 + r4.z);
        pp += gvw*tanhf(q3 + r4.w);
        pp = wsum_(pp);
        if (lane == 0) uu.s.lg[wbb*128 + s] = mk[s] ? -INFINITY : pp;
      }
    }
    __syncthreads();
    if (wvL == 0) {  // waves 0 and 4: softmax per bb
      const float v0 = uu.s.lg[wbb*128 + lane];
      const float v1 = (lane + 64 < S_) ? uu.s.lg[wbb*128 + lane + 64] : -INFINITY;
      const float m  = wmax_(fmaxf(v0, v1));
      const float e0 = expf(v0 - m);
      const float e1 = (lane + 64 < S_) ? expf(v1 - m) : 0.f;
      const float sm = wsum_(e0 + e1);
      uu.s.alpha[wbb*128 + lane] = e0 / sm;
      if (lane + 64 < S_) uu.s.alpha[wbb*128 + lane + 64] = e1 / sm;
    }
    __syncthreads();

    // ---- q = alpha @ enc ----
    { const float* eb = P.enc + (size_t)(b0+half)*S_*H_;
      float a = 0.f;
      for (int s = 0; s < S_; ++s) a += uu.s.alpha[half*128 + s] * eb[s*256 + u];
      uu.s.qL[half*256 + u] = a; }
    __syncthreads();

    // ---- pq = p_bq + q @ p_Wq^T ----
    { float a = P.pbq[u];
      const float4* wq = (const float4*)P.pWqS + u;
      #pragma unroll 4
      for (int kq = 0; kq < 64; ++kq) {
        const float4 w = wq[(size_t)kq*256];
        a += uu.s.qL[half*256 + 4*kq+0]*w.x;
        a += uu.s.qL[half*256 + 4*kq+1]*w.y;
        a += uu.s.qL[half*256 + 4*kq+2]*w.z;
        a += uu.s.qL[half*256 + 4*kq+3]*w.w;
      }
      uu.s.pqL[half*256 + u] = a; }
    __syncthreads();

    // ---- pointer logits ----
    {
      const float q0 = uu.s.pqL[wbb*256 + lane];
      const float q1 = uu.s.pqL[wbb*256 + lane + 64];
      const float q2 = uu.s.pqL[wbb*256 + lane + 128];
      const float q3 = uu.s.pqL[wbb*256 + lane + 192];
      const float* rpb = P.rpS + (size_t)(b0+wbb)*S_*H_;
      const int* mk = maskL + wbb*128;
      for (int is = 0; is < 25; ++is) {
        const int s = is*4 + wvL;
        const float4 r4 = *(const float4*)(rpb + s*256 + lane*4);
        float pp = pvx*tanhf(q0 + r4.x);
        pp += pvy*tanhf(q1 + r4.y);
        pp += pvz*tanhf(q2 + r4.z);
        pp += pvw*tanhf(q3 + r4.w);
        pp = wsum_(pp);
        if (lane == 0) {
          const float v = 10.0f * tanhf(pp);
          uu.s.lp[wbb*128 + s] = mk[s] ? -INFINITY : v;
        }
      }
    }
    __syncthreads();
    if (wvL == 0) {  // waves 0 and 4: probs + sampling per bb
      const int b = b0 + wbb;
      const float v0 = uu.s.lp[wbb*128 + lane];
      const float v1 = (lane + 64 < S_) ? uu.s.lp[wbb*128 + lane + 64] : -INFINITY;
      const float m  = wmax_(fmaxf(v0, v1));
      const float e0 = expf(v0 - m);
      const float e1 = (lane + 64 < S_) ? expf(v1 - m) : 0.f;
      const float sm = wsum_(e0 + e1);
      float* po = P.probs + ((size_t)t*B_ + b)*S_;
      po[lane] = e0 / sm;
      if (lane + 64 < S_) po[lane + 64] = e1 / sm;

      uint32_t k0, k1; threefry2x32_(0u, 1u, 0u, (uint32_t)t, k0, k1);
      uint32_t r0, r1;
      threefry2x32_(k0, k1, 0u, (uint32_t)(b*S_ + lane), r0, r1);
      float z0 = v0 + gumbel_bits_(r0 ^ r1);
      float z1 = -INFINITY;
      if (lane + 64 < S_) {
        uint32_t q0b, q1b;
        threefry2x32_(k0, k1, 0u, (uint32_t)(b*S_ + lane + 64), q0b, q1b);
        z1 = v1 + gumbel_bits_(q0b ^ q1b);
      }
      float bv; int bi;
      if (z1 > z0) { bv = z1; bi = lane + 64; } else { bv = z0; bi = lane; }
      #pragma unroll
      for (int d = 32; d > 0; d >>= 1) {
        const float ov = __shfl_xor(bv, d, 64);
        const int   oi = __shfl_xor(bi, d, 64);
        if (ov > bv || (ov == bv && oi < bi)) { bv = ov; bi = oi; }
      }
      if (lane == 0) {
        P.idxo[t*B_ + b] = (float)bi;
        selL[wbb] = bi;
        maskL[wbb*128 + bi] = 1;
      }
    }
    __syncthreads();
  }
}

extern "C" void kernel_launch(void* const* d_in, const int* in_sizes, int n_in,
                              void* d_out, int out_size, void* d_ws, size_t ws_size,
                              hipStream_t stream) {
  (void)in_sizes; (void)n_in; (void)out_size; (void)ws_size;

  float* ws = (float*)d_ws;
  size_t o = 0;
  float* W4E  = ws + o; o += (size_t)512*1024;
  float* W4D  = ws + o; o += (size_t)512*1024;
  float* b4E  = ws + o; o += 1024;
  float* b4D  = ws + o; o += 1024;
  float* gWqS = ws + o; o += 65536;
  float* pWqS = ws + o; o += 65536;
  float* gWrT = ws + o; o += 65536;
  float* pWrT = ws + o; o += 65536;
  float* enc  = ws + o; o += (size_t)B_*S_*H_;
  float* rgS  = ws + o; o += (size_t)B_*S_*H_;
  float* rpS  = ws + o; o += (size_t)B_*S_*H_;

  PrepParams PP;
  PP.eWih = (const float*)d_in[2];  PP.eWhh = (const float*)d_in[3];
  PP.ebih = (const float*)d_in[4];  PP.ebhh = (const float*)d_in[5];
  PP.dWih = (const float*)d_in[6];  PP.dWhh = (const float*)d_in[7];
  PP.dbih = (const float*)d_in[8];  PP.dbhh = (const float*)d_in[9];
  PP.gWq  = (const float*)d_in[10]; PP.pWq  = (const float*)d_in[15];
  PP.gWr  = (const float*)d_in[12]; PP.pWr  = (const float*)d_in[17];
  PP.W4E = W4E; PP.W4D = W4D; PP.b4E = b4E; PP.b4D = b4D;
  PP.gWqS = gWqS; PP.pWqS = pWqS; PP.gWrT = gWrT; PP.pWrT = pWrT;

  KParams P;
  P.inputs = (const float*)d_in[0];
  P.emb    = (const float*)d_in[1];
  P.gbq    = (const float*)d_in[11];
  P.gbr    = (const float*)d_in[13];
  P.gV     = (const float*)d_in[14];
  P.pbq    = (const float*)d_in[16];
  P.pbr    = (const float*)d_in[18];
  P.pV     = (const float*)d_in[19];
  P.start  = (const float*)d_in[20];
  P.W4E = W4E; P.W4D = W4D; P.b4E = b4E; P.b4D = b4D;
  P.gWqS = gWqS; P.pWqS = pWqS; P.gWrT = gWrT; P.pWrT = pWrT;
  P.enc = enc; P.rgS = rgS; P.rpS = rpS;
  P.probs = (float*)d_out;
  P.idxo  = P.probs + (size_t)S_*B_*S_;

  prep_all<<<2048, 256, 0, stream>>>(PP);
  pointer_net_perb<<<256, 512, 0, stream>>>(P);
}